// Round 15
// baseline (289.520 us; speedup 1.0000x reference)
//
#include <hip/hip_runtime.h>
#include <hip/hip_bf16.h>

#define D_MODEL 512
#define N_HEADS 8
#define HDIM 64
#define D_FF 2048
#define BATCH 64
#define SEQ 500
#define MROWS (BATCH * SEQ)  // 32000

typedef __attribute__((ext_vector_type(8))) short bhalf8;   // 8 bf16 = 4 VGPRs
typedef __attribute__((ext_vector_type(4))) float floatx4;  // MFMA accumulator

#define AS_GLOBAL __attribute__((address_space(1)))
#define AS_LDS __attribute__((address_space(3)))

__device__ __forceinline__ void glds16(const void* g, void* l) {
  __builtin_amdgcn_global_load_lds((const AS_GLOBAL unsigned int*)g,
                                   (AS_LDS unsigned int*)l, 16, 0, 0);
}

__device__ __forceinline__ unsigned short f2bf(float f) {
  __hip_bfloat16 b = __float2bfloat16(f);
  return *reinterpret_cast<unsigned short*>(&b);
}

// ---------------------------------------------------------------------------
// LayerNorm -> bf16 out only. MODE 0: f32 in (LN1). MODE 1: bf16 in (LN2).
// ---------------------------------------------------------------------------
template <int MODE>
__global__ __launch_bounds__(256) void ln_kernel(const void* __restrict__ xin,
                                                 const float* __restrict__ g,
                                                 const float* __restrict__ b,
                                                 __hip_bfloat16* __restrict__ yb) {
  int row = blockIdx.x;
  int t = threadIdx.x;
  float v0, v1;
  if constexpr (MODE == 0) {
    float2 v = ((const float2*)xin)[(size_t)row * 256 + t];
    v0 = v.x; v1 = v.y;
  } else {
    __hip_bfloat162 bv = ((const __hip_bfloat162*)xin)[(size_t)row * 256 + t];
    v0 = __bfloat162float(bv.x); v1 = __bfloat162float(bv.y);
  }
  float s = v0 + v1;
  float sq = v0 * v0 + v1 * v1;
#pragma unroll
  for (int off = 32; off > 0; off >>= 1) {
    s += __shfl_down(s, off, 64);
    sq += __shfl_down(sq, off, 64);
  }
  __shared__ float red[8];
  if ((t & 63) == 0) {
    red[(t >> 6) * 2] = s;
    red[(t >> 6) * 2 + 1] = sq;
  }
  __syncthreads();
  s = red[0] + red[2] + red[4] + red[6];
  sq = red[1] + red[3] + red[5] + red[7];
  float mean = s * (1.0f / 512.0f);
  float var = sq * (1.0f / 512.0f) - mean * mean;
  float r = rsqrtf(var + 1e-6f);
  float2 gg = ((const float2*)g)[t];
  float2 bb = ((const float2*)b)[t];
  float y0 = (v0 - mean) * r * gg.x + bb.x;
  float y1 = (v1 - mean) * r * gg.y + bb.y;
  __hip_bfloat162 bv2;
  bv2.x = __float2bfloat16(y0);
  bv2.y = __float2bfloat16(y1);
  ((__hip_bfloat162*)yb)[(size_t)row * 256 + t] = bv2;
}

// ---------------------------------------------------------------------------
// Transpose + convert fp32 W[K][N] -> bf16 Wt[N][K] (LDS-tiled, 32x32)
// ---------------------------------------------------------------------------
__global__ __launch_bounds__(256) void transpose_bf16(const float* __restrict__ W,
                                                      __hip_bfloat16* __restrict__ Wt,
                                                      int K, int N) {
  __shared__ float tile[32][33];
  int n0 = blockIdx.x * 32, k0 = blockIdx.y * 32;
  int tx = threadIdx.x, ty = threadIdx.y;
#pragma unroll
  for (int j = 0; j < 32; j += 8)
    tile[ty + j][tx] = W[(size_t)(k0 + ty + j) * N + n0 + tx];
  __syncthreads();
#pragma unroll
  for (int j = 0; j < 32; j += 8)
    Wt[(size_t)(n0 + ty + j) * K + k0 + tx] = __float2bfloat16(tile[tx][ty + j]);
}

// ---------------------------------------------------------------------------
// Folded MFMA flash attention with FIXED-MAX softmax + deferred-l (r14).
// ---------------------------------------------------------------------------
__device__ __forceinline__ void attn_tile_step(int jq, int kt, int fr, int kg,
                                               const char* Kb, const char* Vb,
                                               char* Pw, bhalf8 (&qf)[2][2],
                                               floatx4 (&O)[2][4], float (&l)[2][4]) {
  int roff = 32 * jq - 64 * kt;       // 0 or 32 when masking applies
  bool domask = (jq <= 2 * kt + 1);   // diagonal tiles only
#pragma unroll
  for (int mr = 0; mr < 2; ++mr) {
    floatx4 S[4];
#pragma unroll
    for (int nc = 0; nc < 4; ++nc) S[nc] = (floatx4){0.f, 0.f, 0.f, 0.f};
    __builtin_amdgcn_s_setprio(1);
#pragma unroll
    for (int kk = 0; kk < 2; ++kk) {
#pragma unroll
      for (int nc = 0; nc < 4; ++nc) {
        bhalf8 kf = *(const bhalf8*)(Kb + (nc * 16 + fr) * 128 +
                                     (((kk * 4 + kg) ^ (fr & 7)) << 4));
        S[nc] = __builtin_amdgcn_mfma_f32_16x16x32_bf16(qf[mr][kk], kf, S[nc], 0, 0, 0);
      }
    }
    __builtin_amdgcn_s_setprio(0);
    if (domask) {
#pragma unroll
      for (int nc = 0; nc < 4; ++nc)
#pragma unroll
        for (int j = 0; j < 4; ++j)
          if (nc * 16 + fr > roff + mr * 16 + kg * 4 + j) S[nc][j] = -INFINITY;
    }
    // fixed-max softmax: p = exp(s/8 - 66); masked (-inf) -> 0.
    // l accumulates PER-LANE partials only (cross-lane reduce deferred).
    float p[4][4];
#pragma unroll
    for (int nc = 0; nc < 4; ++nc)
#pragma unroll
      for (int j = 0; j < 4; ++j) {
        p[nc][j] = __expf(S[nc][j] * 0.125f - 66.0f);
        l[mr][j] += p[nc][j];
      }
#pragma unroll
    for (int nc = 0; nc < 4; ++nc)
#pragma unroll
      for (int j = 0; j < 4; ++j)
        *(unsigned short*)(Pw + ((kg * 4 + j) * 72 + nc * 16 + fr) * 2) = f2bf(p[nc][j]);
    __builtin_amdgcn_s_setprio(1);
#pragma unroll
    for (int kk = 0; kk < 2; ++kk) {
      bhalf8 pf = *(const bhalf8*)(Pw + fr * 144 + kk * 64 + kg * 16);
#pragma unroll
      for (int nc = 0; nc < 4; ++nc) {
        bhalf8 vf = *(const bhalf8*)(Vb + (nc * 16 + fr) * 144 + kk * 64 + kg * 16);
        O[mr][nc] = __builtin_amdgcn_mfma_f32_16x16x32_bf16(pf, vf, O[mr][nc], 0, 0, 0);
      }
    }
    __builtin_amdgcn_s_setprio(0);
  }
}

__global__ __launch_bounds__(512) void attn_fold(const __hip_bfloat16* __restrict__ hbp,
                                                 __hip_bfloat16* __restrict__ hres) {
  __shared__ unsigned short Ks[2][64 * 64];
  __shared__ unsigned short Vt[2][64 * 72];
  __shared__ unsigned short Ps[8][16 * 72];

  int blk = blockIdx.x;
  int b = blk >> 3, hd = blk & 7;
  int tid = threadIdx.x;
  int w = tid >> 6, lane = tid & 63;
  int fr = lane & 15, kg = lane >> 4;

  const unsigned short* hb = (const unsigned short*)hbp;
  size_t bbase = (size_t)b * SEQ * D_MODEL + hd * HDIM;

  int jH = 15 - w, jL = w;
  bhalf8 qH[2][2], qL[2][2];
#pragma unroll
  for (int mr = 0; mr < 2; ++mr) {
    int rH = 32 * jH + mr * 16 + fr;
    if (rH >= SEQ) rH = SEQ - 1;  // fake rows never written
    int rL = 32 * jL + mr * 16 + fr;
#pragma unroll
    for (int kk = 0; kk < 2; ++kk) {
      qH[mr][kk] = *(const bhalf8*)(hb + bbase + (size_t)rH * D_MODEL + kk * 32 + kg * 8);
      qL[mr][kk] = *(const bhalf8*)(hb + bbase + (size_t)rL * D_MODEL + kk * 32 + kg * 8);
    }
  }

  floatx4 OH[2][4], OL[2][4];
  float lHs[2][4], lLs[2][4];
#pragma unroll
  for (int mr = 0; mr < 2; ++mr)
#pragma unroll
    for (int nc = 0; nc < 4; ++nc) {
      OH[mr][nc] = (floatx4){0.f, 0.f, 0.f, 0.f};
      OL[mr][nc] = (floatx4){0.f, 0.f, 0.f, 0.f};
    }
#pragma unroll
  for (int mr = 0; mr < 2; ++mr)
#pragma unroll
    for (int j = 0; j < 4; ++j) { lHs[mr][j] = 0.f; lLs[mr][j] = 0.f; }

  int krow = w * 8 + (lane >> 3);
  int scb = (lane & 7) ^ (lane >> 3);

  {  // prologue: tile 0
    glds16(hb + bbase + (size_t)krow * D_MODEL + scb * 8, (char*)Ks[0] + w * 1024);
    bhalf8 v0 = *(const bhalf8*)(hb + bbase + (size_t)lane * D_MODEL + w * 8);
#pragma unroll
    for (int i = 0; i < 8; ++i) Vt[0][(w * 8 + i) * 72 + lane] = (unsigned short)v0[i];
  }
  __syncthreads();

  for (int kt = 0; kt < 8; ++kt) {
    int cur = kt & 1;
    bhalf8 vnext;
    if (kt < 7) {  // issue next tile's loads before compute
      int sr = (kt + 1) * 64 + krow;
      if (sr >= SEQ) sr = SEQ - 1;
      glds16(hb + bbase + (size_t)sr * D_MODEL + scb * 8, (char*)Ks[cur ^ 1] + w * 1024);
      int vr = (kt + 1) * 64 + lane;
      if (vr >= SEQ) vr = SEQ - 1;
      vnext = *(const bhalf8*)(hb + bbase + (size_t)vr * D_MODEL + w * 8);
    }

    const char* Kb = (const char*)Ks[cur];
    const char* Vb = (const char*)Vt[cur];
    char* Pw = (char*)Ps[w];
    if (jH >= 2 * kt) attn_tile_step(jH, kt, fr, kg, Kb, Vb, Pw, qH, OH, lHs);
    if (jL >= 2 * kt) attn_tile_step(jL, kt, fr, kg, Kb, Vb, Pw, qL, OL, lLs);

    if (kt < 7) {  // write-late V^T
#pragma unroll
      for (int i = 0; i < 8; ++i)
        Vt[cur ^ 1][(w * 8 + i) * 72 + lane] = (unsigned short)vnext[i];
    }
    __syncthreads();
  }

  // deferred l reduction: row sum = sum over the 16 fr-lanes sharing kg
#pragma unroll
  for (int off = 1; off < 16; off <<= 1)
#pragma unroll
    for (int mr = 0; mr < 2; ++mr)
#pragma unroll
      for (int j = 0; j < 4; ++j) {
        lHs[mr][j] += __shfl_xor(lHs[mr][j], off, 64);
        lLs[mr][j] += __shfl_xor(lLs[mr][j], off, 64);
      }

  // hres = bf16( h + O/l ); residual re-read from hb
#pragma unroll
  for (int mr = 0; mr < 2; ++mr)
#pragma unroll
    for (int j = 0; j < 4; ++j) {
      int qH_row = 32 * jH + mr * 16 + kg * 4 + j;
      if (qH_row < SEQ) {
        float inv = 1.0f / lHs[mr][j];
        size_t ro = bbase + (size_t)qH_row * D_MODEL;
#pragma unroll
        for (int nc = 0; nc < 4; ++nc) {
          size_t idx = ro + nc * 16 + fr;
          float hv = __bfloat162float(hbp[idx]);
          hres[idx] = __float2bfloat16(hv + OH[mr][nc][j] * inv);
        }
      }
      int qL_row = 32 * jL + mr * 16 + kg * 4 + j;
      {
        float inv = 1.0f / lLs[mr][j];
        size_t ro = bbase + (size_t)qL_row * D_MODEL;
#pragma unroll
        for (int nc = 0; nc < 4; ++nc) {
          size_t idx = ro + nc * 16 + fr;
          float hv = __bfloat162float(hbp[idx]);
          hres[idx] = __float2bfloat16(hv + OL[mr][nc][j] * inv);
        }
      }
    }
}

// ---------------------------------------------------------------------------
// m97-replica bf16 MFMA GEMM, 4 blocks/CU + DOUBLE-BUFFER + 1 barrier/tile.
// C = A[M,K] * Bt[N,K]^T. 128x128 tile, BK=32, 4 waves (wave = 64x64 out).
// The one untried combination: r6 had dbuf+1-barrier but at 2 blocks/CU with
// 8-way read conflicts (LDS-pipe-bound, overlap invisible); r12/r14 have
// 4 blocks/CU but single-buffer = serial stage->compute per tile. Here:
// 2 x 16KB buffers (32KB/block x 4 blocks = 128 <= 160KB, occupancy kept),
// per tile: {ds_read from buf[t&1] -> STAGE(t+1)->buf[(t+1)&1] (pinned by
// sched_barrier) -> 16 MFMA -> __syncthreads}. The sync's vmcnt(0) drain is
// covered by the MFMA cluster + 3 co-resident blocks; barrier count halves.
// W-A-R: buf[(t+1)&1] last read at tile t-1, sealed by t-1's sync.
// Conflict-free swizzle (r7, measured 0), both sides (rule 21).
// EPI==1: out_bf16 = relu(acc + bias)
// EPI==2: out_f32  = resid_bf16 + acc + bias (pure store; resid L2-hot)
// ---------------------------------------------------------------------------
template <int EPI>
__global__ __launch_bounds__(256, 4) void gemm97(const unsigned short* __restrict__ A,
                                                 const unsigned short* __restrict__ Bt,
                                                 const float* __restrict__ bias,
                                                 const __hip_bfloat16* __restrict__ resid,
                                                 float* __restrict__ outf,
                                                 __hip_bfloat16* __restrict__ outb,
                                                 int M, int N, int K, int gx) {
  __shared__ __align__(16) char smem[2 * 16384];  // dbuf: As 8KB | Bs 8KB each

  // bijective XCD-chunked swizzle (m204), n-fast linearization
  int nwg = gridDim.x;
  int bid = blockIdx.x;
  int q = nwg >> 3, r = nwg & 7;
  int xcd = bid & 7, lo = bid >> 3;
  int wg = (xcd < r ? xcd * (q + 1) : r * (q + 1) + (xcd - r) * q) + lo;
  int by = wg / gx, bx = wg % gx;
  int m0 = by * 128, n0 = bx * 128;

  int tid = threadIdx.x;
  int w = tid >> 6, lane = tid & 63;
  int wr = (w >> 1) * 64, wc = (w & 1) * 64;
  int fr = lane & 15, kg = lane >> 4;

  // staging: 4 glds16/thread/tile; 1KB chunk c covers rows c*16..c*16+15;
  // wave w owns chunks {w, w+4} of A and of B.
  int srow = lane >> 2;                             // 0..15
  int scol = ((lane & 3) ^ ((lane >> 3) & 3)) * 8;  // pre-swizzled k-slot
  const unsigned short* Ag0 = A + (size_t)(m0 + w * 16 + srow) * K + scol;
  const unsigned short* Ag1 = A + (size_t)(m0 + (w + 4) * 16 + srow) * K + scol;
  const unsigned short* Bg0 = Bt + (size_t)(n0 + w * 16 + srow) * K + scol;
  const unsigned short* Bg1 = Bt + (size_t)(n0 + (w + 4) * 16 + srow) * K + scol;
  int dA0 = w * 1024, dA1 = (w + 4) * 1024;
  int dB0 = 8192 + w * 1024, dB1 = 8192 + (w + 4) * 1024;

  // fragment reads: byte = row*64 + (kg ^ ((row>>1)&3))*16; row&15 == fr
  int swz16 = (kg ^ ((fr >> 1) & 3)) << 4;
  int aoff = (wr + fr) * 64 + swz16;                // + mm*1024
  int boff = 8192 + (wc + fr) * 64 + swz16;         // + nn*1024

  floatx4 acc[4][4];
#pragma unroll
  for (int i = 0; i < 4; ++i)
#pragma unroll
    for (int j = 0; j < 4; ++j) acc[i][j] = (floatx4){0.f, 0.f, 0.f, 0.f};

  int nt = K >> 5;

#define STAGE(t, buf)                                \
  {                                                  \
    char* d = smem + (buf) * 16384;                  \
    glds16(Ag0 + (size_t)(t) * 32, d + dA0);         \
    glds16(Ag1 + (size_t)(t) * 32, d + dA1);         \
    glds16(Bg0 + (size_t)(t) * 32, d + dB0);         \
    glds16(Bg1 + (size_t)(t) * 32, d + dB1);         \
  }

  STAGE(0, 0);
  __syncthreads();  // tile 0 resident

  for (int t = 0; t < nt; ++t) {
    const char* bufp = smem + (t & 1) * 16384;
    if (t + 1 < nt) STAGE(t + 1, (t + 1) & 1);  // issue-early into other buf
    __builtin_amdgcn_sched_barrier(0);          // pin stage before reads/MFMA
    bhalf8 av[4], bv[4];
#pragma unroll
    for (int mm = 0; mm < 4; ++mm) av[mm] = *(const bhalf8*)(bufp + aoff + mm * 1024);
#pragma unroll
    for (int nn = 0; nn < 4; ++nn) bv[nn] = *(const bhalf8*)(bufp + boff + nn * 1024);
    __builtin_amdgcn_s_setprio(1);
#pragma unroll
    for (int mm = 0; mm < 4; ++mm)
#pragma unroll
      for (int nn = 0; nn < 4; ++nn)
        acc[mm][nn] =
            __builtin_amdgcn_mfma_f32_16x16x32_bf16(av[mm], bv[nn], acc[mm][nn], 0, 0, 0);
    __builtin_amdgcn_s_setprio(0);
    __syncthreads();  // vmcnt(0) drain (covered by MFMA + co-resident blocks):
                      // tile t+1 resident; buf[t&1] sealed for overwrite at t+2
  }
#undef STAGE

  // epilogue: C/D layout col=fr, row=kg*4+j (verified m89/m91)
  int grow_base = m0 + wr + kg * 4;
  int gcol_base = n0 + wc + fr;
#pragma unroll
  for (int mm = 0; mm < 4; ++mm) {
#pragma unroll
    for (int nn = 0; nn < 4; ++nn) {
      int gc = gcol_base + nn * 16;
      float bi = bias[gc];
#pragma unroll
      for (int j = 0; j < 4; ++j) {
        int gr = grow_base + mm * 16 + j;
        float v = acc[mm][nn][j] + bi;
        size_t idx = (size_t)gr * N + gc;
        if (EPI == 1) {
          v = v > 0.f ? v : 0.f;
          outb[idx] = __float2bfloat16(v);
        } else {
          outf[idx] = __bfloat162float(resid[idx]) + v;
        }
      }
    }
  }
}

// ---------------------------------------------------------------------------
extern "C" void kernel_launch(void* const* d_in, const int* in_sizes, int n_in,
                              void* d_out, int out_size, void* d_ws, size_t ws_size,
                              hipStream_t stream) {
  const float* x = (const float*)d_in[0];
  const float* ln1g = (const float*)d_in[1];
  const float* ln1b = (const float*)d_in[2];
  const float* ln2g = (const float*)d_in[3];
  const float* ln2b = (const float*)d_in[4];
  const float* W1 = (const float*)d_in[5];
  const float* b1 = (const float*)d_in[6];
  const float* W2 = (const float*)d_in[7];
  const float* b2 = (const float*)d_in[8];
  float* out = (float*)d_out;

  // Workspace layout (233,570,304 B):
  //   h2b:  [0, 32768000)              bf16 (LN2 out; GEMM1 A + GEMM2 resid)
  //   hb:   [65536000, 98304000)       bf16 [32000][512]  (LN1 out)
  //   hresb:[98304000, 131072000)      bf16 (attn out; dead after LN2)
  //   u:    [98304000, 229376000)      bf16 [32000][2048] (aliases dead hresb)
  //   W1t:  [229376000, 231473152)     bf16 [2048][512]
  //   W2t:  [231473152, 233570304)     bf16 [512][2048]
  char* ws = (char*)d_ws;
  __hip_bfloat16* h2b = (__hip_bfloat16*)ws;
  __hip_bfloat16* hb = (__hip_bfloat16*)(ws + 65536000);
  __hip_bfloat16* hresb = (__hip_bfloat16*)(ws + 98304000);
  __hip_bfloat16* u = (__hip_bfloat16*)(ws + 98304000);
  __hip_bfloat16* W1t = (__hip_bfloat16*)(ws + 229376000);
  __hip_bfloat16* W2t = (__hip_bfloat16*)(ws + 231473152);

  transpose_bf16<<<dim3(D_FF / 32, D_MODEL / 32), dim3(32, 8), 0, stream>>>(
      W1, W1t, D_MODEL, D_FF);
  transpose_bf16<<<dim3(D_MODEL / 32, D_FF / 32), dim3(32, 8), 0, stream>>>(
      W2, W2t, D_FF, D_MODEL);

  ln_kernel<0><<<MROWS, 256, 0, stream>>>(x, ln1g, ln1b, hb);

  attn_fold<<<BATCH * N_HEADS, 512, 0, stream>>>(hb, hresb);

  ln_kernel<1><<<MROWS, 256, 0, stream>>>(hresb, ln2g, ln2b, h2b);

  // GEMM1: [32000,512] x [512,2048] -> u ; grid 250x16 = 4000 blocks
  gemm97<1><<<(MROWS / 128) * (D_FF / 128), 256, 0, stream>>>(
      (const unsigned short*)h2b, (const unsigned short*)W1t, b1, nullptr,
      nullptr, u, MROWS, D_FF, D_MODEL, D_FF / 128);
  // GEMM2: [32000,2048] x [2048,512] -> out = h2b + acc + b2 ; 1000 blocks
  gemm97<2><<<(MROWS / 128) * (D_MODEL / 128), 256, 0, stream>>>(
      (const unsigned short*)u, (const unsigned short*)W2t, b2, h2b, out,
      nullptr, MROWS, D_MODEL, D_FF, D_MODEL / 128);
}

// Round 16
// 286.517 us; speedup vs baseline: 1.0105x; 1.0105x over previous
//
#include <hip/hip_runtime.h>
#include <hip/hip_bf16.h>

#define D_MODEL 512
#define N_HEADS 8
#define HDIM 64
#define D_FF 2048
#define BATCH 64
#define SEQ 500
#define MROWS (BATCH * SEQ)  // 32000

typedef __attribute__((ext_vector_type(8))) short bhalf8;   // 8 bf16 = 4 VGPRs
typedef __attribute__((ext_vector_type(4))) float floatx4;  // MFMA accumulator

#define AS_GLOBAL __attribute__((address_space(1)))
#define AS_LDS __attribute__((address_space(3)))

__device__ __forceinline__ void glds16(const void* g, void* l) {
  __builtin_amdgcn_global_load_lds((const AS_GLOBAL unsigned int*)g,
                                   (AS_LDS unsigned int*)l, 16, 0, 0);
}

__device__ __forceinline__ unsigned short f2bf(float f) {
  __hip_bfloat16 b = __float2bfloat16(f);
  return *reinterpret_cast<unsigned short*>(&b);
}

// ---------------------------------------------------------------------------
// LayerNorm -> bf16 out only. MODE 0: f32 in (LN1). MODE 1: bf16 in (LN2).
// ---------------------------------------------------------------------------
template <int MODE>
__global__ __launch_bounds__(256) void ln_kernel(const void* __restrict__ xin,
                                                 const float* __restrict__ g,
                                                 const float* __restrict__ b,
                                                 __hip_bfloat16* __restrict__ yb) {
  int row = blockIdx.x;
  int t = threadIdx.x;
  float v0, v1;
  if constexpr (MODE == 0) {
    float2 v = ((const float2*)xin)[(size_t)row * 256 + t];
    v0 = v.x; v1 = v.y;
  } else {
    __hip_bfloat162 bv = ((const __hip_bfloat162*)xin)[(size_t)row * 256 + t];
    v0 = __bfloat162float(bv.x); v1 = __bfloat162float(bv.y);
  }
  float s = v0 + v1;
  float sq = v0 * v0 + v1 * v1;
#pragma unroll
  for (int off = 32; off > 0; off >>= 1) {
    s += __shfl_down(s, off, 64);
    sq += __shfl_down(sq, off, 64);
  }
  __shared__ float red[8];
  if ((t & 63) == 0) {
    red[(t >> 6) * 2] = s;
    red[(t >> 6) * 2 + 1] = sq;
  }
  __syncthreads();
  s = red[0] + red[2] + red[4] + red[6];
  sq = red[1] + red[3] + red[5] + red[7];
  float mean = s * (1.0f / 512.0f);
  float var = sq * (1.0f / 512.0f) - mean * mean;
  float r = rsqrtf(var + 1e-6f);
  float2 gg = ((const float2*)g)[t];
  float2 bb = ((const float2*)b)[t];
  float y0 = (v0 - mean) * r * gg.x + bb.x;
  float y1 = (v1 - mean) * r * gg.y + bb.y;
  __hip_bfloat162 bv2;
  bv2.x = __float2bfloat16(y0);
  bv2.y = __float2bfloat16(y1);
  ((__hip_bfloat162*)yb)[(size_t)row * 256 + t] = bv2;
}

// ---------------------------------------------------------------------------
// Transpose + convert fp32 W[K][N] -> bf16 Wt[N][K] (LDS-tiled, 32x32)
// ---------------------------------------------------------------------------
__global__ __launch_bounds__(256) void transpose_bf16(const float* __restrict__ W,
                                                      __hip_bfloat16* __restrict__ Wt,
                                                      int K, int N) {
  __shared__ float tile[32][33];
  int n0 = blockIdx.x * 32, k0 = blockIdx.y * 32;
  int tx = threadIdx.x, ty = threadIdx.y;
#pragma unroll
  for (int j = 0; j < 32; j += 8)
    tile[ty + j][tx] = W[(size_t)(k0 + ty + j) * N + n0 + tx];
  __syncthreads();
#pragma unroll
  for (int j = 0; j < 32; j += 8)
    Wt[(size_t)(n0 + ty + j) * K + k0 + tx] = __float2bfloat16(tile[tx][ty + j]);
}

// ---------------------------------------------------------------------------
// Folded MFMA flash attention with FIXED-MAX softmax + deferred-l (r14).
// ---------------------------------------------------------------------------
__device__ __forceinline__ void attn_tile_step(int jq, int kt, int fr, int kg,
                                               const char* Kb, const char* Vb,
                                               char* Pw, bhalf8 (&qf)[2][2],
                                               floatx4 (&O)[2][4], float (&l)[2][4]) {
  int roff = 32 * jq - 64 * kt;       // 0 or 32 when masking applies
  bool domask = (jq <= 2 * kt + 1);   // diagonal tiles only
#pragma unroll
  for (int mr = 0; mr < 2; ++mr) {
    floatx4 S[4];
#pragma unroll
    for (int nc = 0; nc < 4; ++nc) S[nc] = (floatx4){0.f, 0.f, 0.f, 0.f};
    __builtin_amdgcn_s_setprio(1);
#pragma unroll
    for (int kk = 0; kk < 2; ++kk) {
#pragma unroll
      for (int nc = 0; nc < 4; ++nc) {
        bhalf8 kf = *(const bhalf8*)(Kb + (nc * 16 + fr) * 128 +
                                     (((kk * 4 + kg) ^ (fr & 7)) << 4));
        S[nc] = __builtin_amdgcn_mfma_f32_16x16x32_bf16(qf[mr][kk], kf, S[nc], 0, 0, 0);
      }
    }
    __builtin_amdgcn_s_setprio(0);
    if (domask) {
#pragma unroll
      for (int nc = 0; nc < 4; ++nc)
#pragma unroll
        for (int j = 0; j < 4; ++j)
          if (nc * 16 + fr > roff + mr * 16 + kg * 4 + j) S[nc][j] = -INFINITY;
    }
    // fixed-max softmax: p = exp(s/8 - 66); masked (-inf) -> 0.
    // l accumulates PER-LANE partials only (cross-lane reduce deferred).
    float p[4][4];
#pragma unroll
    for (int nc = 0; nc < 4; ++nc)
#pragma unroll
      for (int j = 0; j < 4; ++j) {
        p[nc][j] = __expf(S[nc][j] * 0.125f - 66.0f);
        l[mr][j] += p[nc][j];
      }
#pragma unroll
    for (int nc = 0; nc < 4; ++nc)
#pragma unroll
      for (int j = 0; j < 4; ++j)
        *(unsigned short*)(Pw + ((kg * 4 + j) * 72 + nc * 16 + fr) * 2) = f2bf(p[nc][j]);
    __builtin_amdgcn_s_setprio(1);
#pragma unroll
    for (int kk = 0; kk < 2; ++kk) {
      bhalf8 pf = *(const bhalf8*)(Pw + fr * 144 + kk * 64 + kg * 16);
#pragma unroll
      for (int nc = 0; nc < 4; ++nc) {
        bhalf8 vf = *(const bhalf8*)(Vb + (nc * 16 + fr) * 144 + kk * 64 + kg * 16);
        O[mr][nc] = __builtin_amdgcn_mfma_f32_16x16x32_bf16(pf, vf, O[mr][nc], 0, 0, 0);
      }
    }
    __builtin_amdgcn_s_setprio(0);
  }
}

__global__ __launch_bounds__(512) void attn_fold(const __hip_bfloat16* __restrict__ hbp,
                                                 __hip_bfloat16* __restrict__ hres) {
  __shared__ unsigned short Ks[2][64 * 64];
  __shared__ unsigned short Vt[2][64 * 72];
  __shared__ unsigned short Ps[8][16 * 72];

  int blk = blockIdx.x;
  int b = blk >> 3, hd = blk & 7;
  int tid = threadIdx.x;
  int w = tid >> 6, lane = tid & 63;
  int fr = lane & 15, kg = lane >> 4;

  const unsigned short* hb = (const unsigned short*)hbp;
  size_t bbase = (size_t)b * SEQ * D_MODEL + hd * HDIM;

  int jH = 15 - w, jL = w;
  bhalf8 qH[2][2], qL[2][2];
#pragma unroll
  for (int mr = 0; mr < 2; ++mr) {
    int rH = 32 * jH + mr * 16 + fr;
    if (rH >= SEQ) rH = SEQ - 1;  // fake rows never written
    int rL = 32 * jL + mr * 16 + fr;
#pragma unroll
    for (int kk = 0; kk < 2; ++kk) {
      qH[mr][kk] = *(const bhalf8*)(hb + bbase + (size_t)rH * D_MODEL + kk * 32 + kg * 8);
      qL[mr][kk] = *(const bhalf8*)(hb + bbase + (size_t)rL * D_MODEL + kk * 32 + kg * 8);
    }
  }

  floatx4 OH[2][4], OL[2][4];
  float lHs[2][4], lLs[2][4];
#pragma unroll
  for (int mr = 0; mr < 2; ++mr)
#pragma unroll
    for (int nc = 0; nc < 4; ++nc) {
      OH[mr][nc] = (floatx4){0.f, 0.f, 0.f, 0.f};
      OL[mr][nc] = (floatx4){0.f, 0.f, 0.f, 0.f};
    }
#pragma unroll
  for (int mr = 0; mr < 2; ++mr)
#pragma unroll
    for (int j = 0; j < 4; ++j) { lHs[mr][j] = 0.f; lLs[mr][j] = 0.f; }

  int krow = w * 8 + (lane >> 3);
  int scb = (lane & 7) ^ (lane >> 3);

  {  // prologue: tile 0
    glds16(hb + bbase + (size_t)krow * D_MODEL + scb * 8, (char*)Ks[0] + w * 1024);
    bhalf8 v0 = *(const bhalf8*)(hb + bbase + (size_t)lane * D_MODEL + w * 8);
#pragma unroll
    for (int i = 0; i < 8; ++i) Vt[0][(w * 8 + i) * 72 + lane] = (unsigned short)v0[i];
  }
  __syncthreads();

  for (int kt = 0; kt < 8; ++kt) {
    int cur = kt & 1;
    bhalf8 vnext;
    if (kt < 7) {  // issue next tile's loads before compute
      int sr = (kt + 1) * 64 + krow;
      if (sr >= SEQ) sr = SEQ - 1;
      glds16(hb + bbase + (size_t)sr * D_MODEL + scb * 8, (char*)Ks[cur ^ 1] + w * 1024);
      int vr = (kt + 1) * 64 + lane;
      if (vr >= SEQ) vr = SEQ - 1;
      vnext = *(const bhalf8*)(hb + bbase + (size_t)vr * D_MODEL + w * 8);
    }

    const char* Kb = (const char*)Ks[cur];
    const char* Vb = (const char*)Vt[cur];
    char* Pw = (char*)Ps[w];
    if (jH >= 2 * kt) attn_tile_step(jH, kt, fr, kg, Kb, Vb, Pw, qH, OH, lHs);
    if (jL >= 2 * kt) attn_tile_step(jL, kt, fr, kg, Kb, Vb, Pw, qL, OL, lLs);

    if (kt < 7) {  // write-late V^T
#pragma unroll
      for (int i = 0; i < 8; ++i)
        Vt[cur ^ 1][(w * 8 + i) * 72 + lane] = (unsigned short)vnext[i];
    }
    __syncthreads();
  }

  // deferred l reduction: row sum = sum over the 16 fr-lanes sharing kg
#pragma unroll
  for (int off = 1; off < 16; off <<= 1)
#pragma unroll
    for (int mr = 0; mr < 2; ++mr)
#pragma unroll
      for (int j = 0; j < 4; ++j) {
        lHs[mr][j] += __shfl_xor(lHs[mr][j], off, 64);
        lLs[mr][j] += __shfl_xor(lLs[mr][j], off, 64);
      }

  // hres = bf16( h + O/l ); residual re-read from hb
#pragma unroll
  for (int mr = 0; mr < 2; ++mr)
#pragma unroll
    for (int j = 0; j < 4; ++j) {
      int qH_row = 32 * jH + mr * 16 + kg * 4 + j;
      if (qH_row < SEQ) {
        float inv = 1.0f / lHs[mr][j];
        size_t ro = bbase + (size_t)qH_row * D_MODEL;
#pragma unroll
        for (int nc = 0; nc < 4; ++nc) {
          size_t idx = ro + nc * 16 + fr;
          float hv = __bfloat162float(hbp[idx]);
          hres[idx] = __float2bfloat16(hv + OH[mr][nc][j] * inv);
        }
      }
      int qL_row = 32 * jL + mr * 16 + kg * 4 + j;
      {
        float inv = 1.0f / lLs[mr][j];
        size_t ro = bbase + (size_t)qL_row * D_MODEL;
#pragma unroll
        for (int nc = 0; nc < 4; ++nc) {
          size_t idx = ro + nc * 16 + fr;
          float hv = __bfloat162float(hbp[idx]);
          hres[idx] = __float2bfloat16(hv + OL[mr][nc][j] * inv);
        }
      }
    }
}

// ---------------------------------------------------------------------------
// m97-replica bf16 MFMA GEMM at 4 blocks/CU -- r14 configuration RESTORED
// (measured best: GEMM1/GEMM2 ~93 us, MfmaUtil 31%, total 287.4 us).
// r15's dbuf+1-barrier variant was flat-to-negative and is withdrawn.
// C = A[M,K] * Bt[N,K]^T. 128x128 tile, BK=32, 4 waves (wave = 64x64 out),
// single-buffered 16 KiB LDS, plain 2-barrier flow. __launch_bounds__(256,4):
// 120 regs/lane -> 4 blocks/CU (TLP curve: 2blk 20% / 3blk 23.6% / 4blk
// 30.6% MfmaUtil, saturated -- the only lever that moved the pin across 13
// GEMM variants; m114 cross-block-TLP mechanism).
// Conflict-free swizzle (r7, measured 0), both sides (rule 21).
// EPI==1: out_bf16 = relu(acc + bias)
// EPI==2: out_f32  = resid_bf16 + acc + bias (pure store; resid L2-hot)
// ---------------------------------------------------------------------------
template <int EPI>
__global__ __launch_bounds__(256, 4) void gemm97(const unsigned short* __restrict__ A,
                                                 const unsigned short* __restrict__ Bt,
                                                 const float* __restrict__ bias,
                                                 const __hip_bfloat16* __restrict__ resid,
                                                 float* __restrict__ outf,
                                                 __hip_bfloat16* __restrict__ outb,
                                                 int M, int N, int K, int gx) {
  __shared__ __align__(16) char smem[16384];  // As 8KB | Bs 8KB

  // bijective XCD-chunked swizzle (m204), n-fast linearization
  int nwg = gridDim.x;
  int bid = blockIdx.x;
  int q = nwg >> 3, r = nwg & 7;
  int xcd = bid & 7, lo = bid >> 3;
  int wg = (xcd < r ? xcd * (q + 1) : r * (q + 1) + (xcd - r) * q) + lo;
  int by = wg / gx, bx = wg % gx;
  int m0 = by * 128, n0 = bx * 128;

  int tid = threadIdx.x;
  int w = tid >> 6, lane = tid & 63;
  int wr = (w >> 1) * 64, wc = (w & 1) * 64;
  int fr = lane & 15, kg = lane >> 4;

  // staging: 4 glds16/thread/tile; 1KB chunk c covers rows c*16..c*16+15;
  // wave w owns chunks {w, w+4} of A and of B.
  int srow = lane >> 2;                             // 0..15
  int scol = ((lane & 3) ^ ((lane >> 3) & 3)) * 8;  // pre-swizzled k-slot
  const unsigned short* Ag0 = A + (size_t)(m0 + w * 16 + srow) * K + scol;
  const unsigned short* Ag1 = A + (size_t)(m0 + (w + 4) * 16 + srow) * K + scol;
  const unsigned short* Bg0 = Bt + (size_t)(n0 + w * 16 + srow) * K + scol;
  const unsigned short* Bg1 = Bt + (size_t)(n0 + (w + 4) * 16 + srow) * K + scol;
  char* dA0 = smem + w * 1024;
  char* dA1 = smem + (w + 4) * 1024;
  char* dB0 = smem + 8192 + w * 1024;
  char* dB1 = smem + 8192 + (w + 4) * 1024;

  // fragment reads: byte = row*64 + (kg ^ ((row>>1)&3))*16; row&15 == fr
  int swz16 = (kg ^ ((fr >> 1) & 3)) << 4;
  const char* abase = smem + (wr + fr) * 64 + swz16;         // + mm*1024
  const char* bbase = smem + 8192 + (wc + fr) * 64 + swz16;  // + nn*1024

  floatx4 acc[4][4];
#pragma unroll
  for (int i = 0; i < 4; ++i)
#pragma unroll
    for (int j = 0; j < 4; ++j) acc[i][j] = (floatx4){0.f, 0.f, 0.f, 0.f};

  int nt = K >> 5;
  for (int t = 0; t < nt; ++t) {
    glds16(Ag0 + (size_t)t * 32, dA0);
    glds16(Ag1 + (size_t)t * 32, dA1);
    glds16(Bg0 + (size_t)t * 32, dB0);
    glds16(Bg1 + (size_t)t * 32, dB1);
    __syncthreads();  // drains vmcnt: tile resident

    bhalf8 av[4], bv[4];
#pragma unroll
    for (int mm = 0; mm < 4; ++mm) av[mm] = *(const bhalf8*)(abase + mm * 1024);
#pragma unroll
    for (int nn = 0; nn < 4; ++nn) bv[nn] = *(const bhalf8*)(bbase + nn * 1024);
#pragma unroll
    for (int mm = 0; mm < 4; ++mm)
#pragma unroll
      for (int nn = 0; nn < 4; ++nn)
        acc[mm][nn] =
            __builtin_amdgcn_mfma_f32_16x16x32_bf16(av[mm], bv[nn], acc[mm][nn], 0, 0, 0);
    __syncthreads();  // readers done before next stage overwrites
  }

  // epilogue: C/D layout col=fr, row=kg*4+j (verified m89/m91)
  int grow_base = m0 + wr + kg * 4;
  int gcol_base = n0 + wc + fr;
#pragma unroll
  for (int mm = 0; mm < 4; ++mm) {
#pragma unroll
    for (int nn = 0; nn < 4; ++nn) {
      int gc = gcol_base + nn * 16;
      float bi = bias[gc];
#pragma unroll
      for (int j = 0; j < 4; ++j) {
        int gr = grow_base + mm * 16 + j;
        float v = acc[mm][nn][j] + bi;
        size_t idx = (size_t)gr * N + gc;
        if (EPI == 1) {
          v = v > 0.f ? v : 0.f;
          outb[idx] = __float2bfloat16(v);
        } else {
          outf[idx] = __bfloat162float(resid[idx]) + v;
        }
      }
    }
  }
}

// ---------------------------------------------------------------------------
extern "C" void kernel_launch(void* const* d_in, const int* in_sizes, int n_in,
                              void* d_out, int out_size, void* d_ws, size_t ws_size,
                              hipStream_t stream) {
  const float* x = (const float*)d_in[0];
  const float* ln1g = (const float*)d_in[1];
  const float* ln1b = (const float*)d_in[2];
  const float* ln2g = (const float*)d_in[3];
  const float* ln2b = (const float*)d_in[4];
  const float* W1 = (const float*)d_in[5];
  const float* b1 = (const float*)d_in[6];
  const float* W2 = (const float*)d_in[7];
  const float* b2 = (const float*)d_in[8];
  float* out = (float*)d_out;

  // Workspace layout (233,570,304 B):
  //   h2b:  [0, 32768000)              bf16 (LN2 out; GEMM1 A + GEMM2 resid)
  //   hb:   [65536000, 98304000)       bf16 [32000][512]  (LN1 out)
  //   hresb:[98304000, 131072000)      bf16 (attn out; dead after LN2)
  //   u:    [98304000, 229376000)      bf16 [32000][2048] (aliases dead hresb)
  //   W1t:  [229376000, 231473152)     bf16 [2048][512]
  //   W2t:  [231473152, 233570304)     bf16 [512][2048]
  char* ws = (char*)d_ws;
  __hip_bfloat16* h2b = (__hip_bfloat16*)ws;
  __hip_bfloat16* hb = (__hip_bfloat16*)(ws + 65536000);
  __hip_bfloat16* hresb = (__hip_bfloat16*)(ws + 98304000);
  __hip_bfloat16* u = (__hip_bfloat16*)(ws + 98304000);
  __hip_bfloat16* W1t = (__hip_bfloat16*)(ws + 229376000);
  __hip_bfloat16* W2t = (__hip_bfloat16*)(ws + 231473152);

  transpose_bf16<<<dim3(D_FF / 32, D_MODEL / 32), dim3(32, 8), 0, stream>>>(
      W1, W1t, D_MODEL, D_FF);
  transpose_bf16<<<dim3(D_MODEL / 32, D_FF / 32), dim3(32, 8), 0, stream>>>(
      W2, W2t, D_FF, D_MODEL);

  ln_kernel<0><<<MROWS, 256, 0, stream>>>(x, ln1g, ln1b, hb);

  attn_fold<<<BATCH * N_HEADS, 512, 0, stream>>>(hb, hresb);

  ln_kernel<1><<<MROWS, 256, 0, stream>>>(hresb, ln2g, ln2b, h2b);

  // GEMM1: [32000,512] x [512,2048] -> u ; grid 250x16 = 4000 blocks
  gemm97<1><<<(MROWS / 128) * (D_FF / 128), 256, 0, stream>>>(
      (const unsigned short*)h2b, (const unsigned short*)W1t, b1, nullptr,
      nullptr, u, MROWS, D_FF, D_MODEL, D_FF / 128);
  // GEMM2: [32000,2048] x [2048,512] -> out = h2b + acc + b2 ; 1000 blocks
  gemm97<2><<<(MROWS / 128) * (D_MODEL / 128), 256, 0, stream>>>(
      (const unsigned short*)u, (const unsigned short*)W2t, b2, h2b, out,
      nullptr, MROWS, D_MODEL, D_FF, D_MODEL / 128);
}